// Round 1
// baseline (914.742 us; speedup 1.0000x reference)
//
#include <hip/hip_runtime.h>
#include <cstdint>

typedef unsigned short ushort_t;
typedef __bf16 bf16x8 __attribute__((ext_vector_type(8)));
typedef float f32x4 __attribute__((ext_vector_type(4)));
typedef uint32_t u32x4 __attribute__((ext_vector_type(4)));

#define RMS_EPS 1.1920928955078125e-07f
// sizes: B=8 T=4096 C=256 Wh=1024 E=8 K=2
// tokens NT=32768, pairs NP=65536

__device__ __forceinline__ ushort_t f2bf(float f) {
  uint32_t u = __builtin_bit_cast(uint32_t, f);
  u += 0x7fffu + ((u >> 16) & 1u);   // RNE
  return (ushort_t)(u >> 16);
}

__device__ __forceinline__ bf16x8 ld_g16(const ushort_t* p) {
  return __builtin_bit_cast(bf16x8, *reinterpret_cast<const u32x4*>(p));
}

// ---- RMSNorm + cast to bf16: one wave per token (64 lanes x float4 = 256) ----
__global__ void rmsnorm_cast(const float* __restrict__ x, const float* __restrict__ w,
                             ushort_t* __restrict__ xn) {
  int token = blockIdx.x * 4 + (threadIdx.x >> 6);
  int lane = threadIdx.x & 63;
  const float4* row = reinterpret_cast<const float4*>(x + (size_t)token * 256);
  float4 v = row[lane];
  float s = v.x * v.x + v.y * v.y + v.z * v.z + v.w * v.w;
#pragma unroll
  for (int off = 1; off < 64; off <<= 1) s += __shfl_xor(s, off);
  float inv = rsqrtf(s * (1.0f / 256.0f) + RMS_EPS);
  const float4* wr = reinterpret_cast<const float4*>(w);
  float4 wv = wr[lane];
  ushort4 o;
  o.x = f2bf(v.x * inv * wv.x);
  o.y = f2bf(v.y * inv * wv.y);
  o.z = f2bf(v.z * inv * wv.z);
  o.w = f2bf(v.w * inv * wv.w);
  *reinterpret_cast<ushort4*>(xn + (size_t)token * 256 + lane * 4) = o;
}

// ---- transpose + cast fp32 [R][S] -> bf16 [S][R], per expert (blockIdx.z) ----
__global__ void transpose_cast(const float* __restrict__ src, ushort_t* __restrict__ dst,
                               int R, int S) {
  __shared__ ushort_t tile[64][65];   // 65: 2-way-max bank aliasing on both phases
  size_t mo = (size_t)blockIdx.z * R * S;
  int s0 = blockIdx.x * 64, r0 = blockIdx.y * 64;
  int tx = threadIdx.x & 63, ty = threadIdx.x >> 6;
  for (int i = ty; i < 64; i += 4)
    tile[i][tx] = f2bf(src[mo + (size_t)(r0 + i) * S + s0 + tx]);
  __syncthreads();
  for (int i = ty; i < 64; i += 4)
    dst[mo + (size_t)(s0 + i) * R + r0 + tx] = tile[tx][i];
}

// ---- route (t,k) pairs into per-expert lists ----
__global__ void route_pairs(const int* __restrict__ eids, int* __restrict__ cnt,
                            int* __restrict__ lists) {
  __shared__ int lcnt[8], lbase[8];
  int tid = threadIdx.x;
  if (tid < 8) lcnt[tid] = 0;
  __syncthreads();
  int p = blockIdx.x * 256 + tid;
  int e = eids[p];
  int lpos = atomicAdd(&lcnt[e], 1);
  __syncthreads();
  if (tid < 8) lbase[tid] = atomicAdd(&cnt[tid], lcnt[tid]);
  __syncthreads();
  lists[e * 65536 + lbase[e] + lpos] = p;
}

// ---- fused expert MLP: 128 pairs/block, 8 waves, wave owns 16 rows ----
// GEMM1: h[16,32-chunk] = xn[16,256] @ W1t^T ; GELU ; LDS relayout ;
// GEMM2: y[16,256] += h[16,32] @ W2 chunk. MFMA 16x16x32 bf16.
__global__ __launch_bounds__(512) void moe_mlp(
    const ushort_t* __restrict__ xn,   // [32768][256] bf16
    const ushort_t* __restrict__ w1t,  // [8][1024][256] bf16 (w-major, contiguous c)
    const ushort_t* __restrict__ w2t,  // [8][256][1024] bf16 (c-major, contiguous w)
    const float* __restrict__ b1,      // [8][1024]
    const float* __restrict__ b2,      // [8][256]
    const int* __restrict__ cnt,       // [8]
    const int* __restrict__ lists,     // [8][65536]
    float* __restrict__ out)           // [65536][256]
{
  int e = blockIdx.y;
  int n_e = cnt[e];
  int start = blockIdx.x * 128;
  if (start >= n_e) return;

  __shared__ int prs[128];
  __shared__ __align__(16) ushort_t hlds[8][16][40];  // per-wave 16x32 (+8 pad), 16B-aligned rows

  int tid = threadIdx.x;
  if (tid < 128) {
    int idx = start + tid;
    prs[tid] = (idx < n_e) ? lists[e * 65536 + idx] : 0;  // pad -> token 0, masked on store
  }
  __syncthreads();

  int wave = tid >> 6, lane = tid & 63;
  int l16 = lane & 15, quad = lane >> 4;

  // A-fragments for this wave's 16 tokens, full K=256, held in registers (32 VGPR)
  int tok = prs[wave * 16 + l16] >> 1;
  bf16x8 afr[8];
  const u32x4* arow = reinterpret_cast<const u32x4*>(xn + (size_t)tok * 256);
#pragma unroll
  for (int kk = 0; kk < 8; ++kk)
    afr[kk] = __builtin_bit_cast(bf16x8, arow[kk * 4 + quad]);  // A[m=l16][k=kk*32+quad*8+j]

  const ushort_t* w1e = w1t + (size_t)e * 262144;
  const ushort_t* w2e = w2t + (size_t)e * 262144;
  const float* b1e = b1 + e * 1024;
  const float* b2e = b2 + e * 256;

  f32x4 acc[16];
#pragma unroll
  for (int i = 0; i < 16; ++i) acc[i] = (f32x4){0.f, 0.f, 0.f, 0.f};

  ushort_t* hl = &hlds[wave][0][0];

  for (int ch = 0; ch < 32; ++ch) {
    int w0 = ch * 32;
    f32x4 h1[2];
    h1[0] = (f32x4){0.f, 0.f, 0.f, 0.f};
    h1[1] = (f32x4){0.f, 0.f, 0.f, 0.f};
    // GEMM1: [16 tokens x 32 w] over K=256
#pragma unroll
    for (int kk = 0; kk < 8; ++kk) {
#pragma unroll
      for (int nt = 0; nt < 2; ++nt) {
        // B[k=c][n=w]: lane reads W1t[w0+nt*16+l16][kk*32+quad*8 ..+8)
        const ushort_t* bp = w1e + (size_t)(w0 + nt * 16 + l16) * 256 + kk * 32 + quad * 8;
        h1[nt] = __builtin_amdgcn_mfma_f32_16x16x32_bf16(afr[kk], ld_g16(bp), h1[nt], 0, 0, 0);
      }
    }
    // bias + GELU (tanh approx, |err|<3e-3) + relayout C->A via wave-private LDS
#pragma unroll
    for (int nt = 0; nt < 2; ++nt) {
      float bias = b1e[w0 + nt * 16 + l16];
#pragma unroll
      for (int r = 0; r < 4; ++r) {
        float v = h1[nt][r] + bias;                       // D: row=quad*4+r, col=nt*16+l16
        float z = 0.7978845608028654f * (v + 0.044715f * v * v * v);
        float t = 1.0f - 2.0f / (1.0f + __expf(2.0f * z));
        float g = 0.5f * v * (1.0f + t);
        hl[(quad * 4 + r) * 40 + nt * 16 + l16] = f2bf(g);
      }
    }
    // A-frag for GEMM2: h[m=l16][k=quad*8..+8), contiguous 16B in LDS (wave-local, no barrier)
    bf16x8 a2 = *reinterpret_cast<const bf16x8*>(hl + l16 * 40 + quad * 8);
    // GEMM2: y[16,256] += h[16,32] @ W2[32,256]
#pragma unroll
    for (int ct = 0; ct < 16; ++ct) {
      // B[k=w][n=c]: lane reads W2t[ct*16+l16][w0+quad*8 ..+8)
      const ushort_t* bp = w2e + (size_t)(ct * 16 + l16) * 1024 + w0 + quad * 8;
      acc[ct] = __builtin_amdgcn_mfma_f32_16x16x32_bf16(a2, ld_g16(bp), acc[ct], 0, 0, 0);
    }
  }

  // epilogue: +b2, masked scatter store (out row = pair index p = t*2+k)
  int myp[4], mok[4];
#pragma unroll
  for (int r = 0; r < 4; ++r) {
    int m = quad * 4 + r;
    myp[r] = prs[wave * 16 + m];
    mok[r] = (start + wave * 16 + m) < n_e;
  }
#pragma unroll
  for (int ct = 0; ct < 16; ++ct) {
    float bias = b2e[ct * 16 + l16];
#pragma unroll
    for (int r = 0; r < 4; ++r) {
      if (mok[r])
        out[(size_t)myp[r] * 256 + ct * 16 + l16] = acc[ct][r] + bias;
    }
  }
}

extern "C" void kernel_launch(void* const* d_in, const int* in_sizes, int n_in,
                              void* d_out, int out_size, void* d_ws, size_t ws_size,
                              hipStream_t stream) {
  const float* x  = (const float*)d_in[0];
  const float* rw = (const float*)d_in[1];
  const float* W1 = (const float*)d_in[2];
  const float* b1 = (const float*)d_in[3];
  const float* W2 = (const float*)d_in[4];
  const float* b2 = (const float*)d_in[5];
  const int* eids = (const int*)d_in[6];
  float* out = (float*)d_out;

  char* ws = (char*)d_ws;
  ushort_t* xn  = (ushort_t*)(ws);              // 32768*256*2      = 16,777,216 B
  ushort_t* w1t = (ushort_t*)(ws + 16777216);   // 8*1024*256*2     =  4,194,304 B
  ushort_t* w2t = (ushort_t*)(ws + 20971520);   // 8*256*1024*2     =  4,194,304 B
  int* cnt      = (int*)(ws + 25165824);        // 8*4 (+pad)
  int* lists    = (int*)(ws + 25166080);        // 8*65536*4        =  2,097,152 B
                                                // total ~27.3 MB of ws

  hipMemsetAsync(cnt, 0, 8 * sizeof(int), stream);
  rmsnorm_cast<<<8192, 256, 0, stream>>>(x, rw, xn);
  transpose_cast<<<dim3(16, 4, 8), 256, 0, stream>>>(W1, w1t, 256, 1024);
  transpose_cast<<<dim3(4, 16, 8), 256, 0, stream>>>(W2, w2t, 1024, 256);
  route_pairs<<<256, 256, 0, stream>>>(eids, cnt, lists);
  // worst case one expert gets all 65536 pairs -> 512 tiles; empty tiles exit early
  moe_mlp<<<dim3(512, 8), 512, 0, stream>>>(xn, w1t, w2t, b1, b2, cnt, lists, out);
}

// Round 2
// 268.783 us; speedup vs baseline: 3.4033x; 3.4033x over previous
//
#include <hip/hip_runtime.h>
#include <cstdint>

typedef unsigned short ushort_t;
typedef __bf16 bf16x8 __attribute__((ext_vector_type(8)));
typedef ushort_t u16x8 __attribute__((ext_vector_type(8)));
typedef float f32x4 __attribute__((ext_vector_type(4)));
typedef uint32_t u32x4 __attribute__((ext_vector_type(4)));

#define RMS_EPS 1.1920928955078125e-07f
// B=8 T=4096 C=256 Wh=1024 E=8 K=2 ; tokens NT=32768, pairs NP=65536

__device__ __forceinline__ ushort_t f2bf(float f) {
  uint32_t u = __builtin_bit_cast(uint32_t, f);
  u += 0x7fffu + ((u >> 16) & 1u);   // RNE
  return (ushort_t)(u >> 16);
}

__device__ __forceinline__ void g2l16(const ushort_t* g, ushort_t* l) {
  __builtin_amdgcn_global_load_lds(
      (const __attribute__((address_space(1))) uint32_t*)g,
      (__attribute__((address_space(3))) uint32_t*)l, 16, 0, 0);
}

// ---- RMSNorm + cast to bf16: one wave per token ----
__global__ void rmsnorm_cast(const float* __restrict__ x, const float* __restrict__ w,
                             ushort_t* __restrict__ xn) {
  int token = blockIdx.x * 4 + (threadIdx.x >> 6);
  int lane = threadIdx.x & 63;
  const float4* row = reinterpret_cast<const float4*>(x + (size_t)token * 256);
  float4 v = row[lane];
  float s = v.x * v.x + v.y * v.y + v.z * v.z + v.w * v.w;
#pragma unroll
  for (int off = 1; off < 64; off <<= 1) s += __shfl_xor(s, off);
  float inv = rsqrtf(s * (1.0f / 256.0f) + RMS_EPS);
  const float4* wr = reinterpret_cast<const float4*>(w);
  float4 wv = wr[lane];
  ushort4 o;
  o.x = f2bf(v.x * inv * wv.x);
  o.y = f2bf(v.y * inv * wv.y);
  o.z = f2bf(v.z * inv * wv.z);
  o.w = f2bf(v.w * inv * wv.w);
  *reinterpret_cast<ushort4*>(xn + (size_t)token * 256 + lane * 4) = o;
}

// ---- pack W1/W2 into MFMA B-fragment order, bf16 ----
// w1f unit U = e*32768 + ch*1024 + kk*128 + nt*64 + lane : 8 elems
//   content[j] = W1[e][kk*32+quad*8+j][ch*32+nt*16+l16]
// w2f unit U = e*32768 + ch*1024 + ct*64 + lane
//   content[j] = W2[e][ch*32+quad*8+j][ct*16+l16]
__global__ void pack_w(const float* __restrict__ W1, const float* __restrict__ W2,
                       ushort_t* __restrict__ w1f, ushort_t* __restrict__ w2f) {
  int U = blockIdx.x * 256 + threadIdx.x;
  int isW2 = (U >= 262144);
  U &= 262143;
  int lane = U & 63, l16 = lane & 15, quad = lane >> 4;
  int e = U >> 15;
  int ch = (U >> 10) & 31;
  u16x8 o;
  if (!isW2) {
    int nt = (U >> 6) & 1, kk = (U >> 7) & 7;
    const float* s = W1 + ((size_t)e << 18) +
                     (size_t)(kk * 32 + quad * 8) * 1024 + ch * 32 + nt * 16 + l16;
#pragma unroll
    for (int j = 0; j < 8; ++j) o[j] = f2bf(s[(size_t)j * 1024]);
    *reinterpret_cast<u16x8*>(w1f + (size_t)U * 8) = o;
  } else {
    int ct = (U >> 6) & 15;
    const float* s = W2 + ((size_t)e << 18) +
                     (size_t)(ch * 32 + quad * 8) * 256 + ct * 16 + l16;
#pragma unroll
    for (int j = 0; j < 8; ++j) o[j] = f2bf(s[(size_t)j * 256]);
    *reinterpret_cast<u16x8*>(w2f + (size_t)U * 8) = o;
  }
}

// ---- route (t,k) pairs into per-expert lists ----
__global__ void route_pairs(const int* __restrict__ eids, int* __restrict__ cnt,
                            int* __restrict__ lists) {
  __shared__ int lcnt[8], lbase[8];
  int tid = threadIdx.x;
  if (tid < 8) lcnt[tid] = 0;
  __syncthreads();
  int p = blockIdx.x * 256 + tid;
  int e = eids[p];
  int lpos = atomicAdd(&lcnt[e], 1);
  __syncthreads();
  if (tid < 8) lbase[tid] = atomicAdd(&cnt[tid], lcnt[tid]);
  __syncthreads();
  lists[e * 65536 + lbase[e] + lpos] = p;
}

// ---- fused expert MLP ----
// Flat grid; block = 128 pairs, 4 waves x 32 rows (2 m-tiles).
// Per K-chunk (32 w's): LDS-staged W1/W2 fragments (double-buffered,
// global_load_lds w16), GEMM1 -> GELU -> wave-private LDS relayout -> GEMM2.
__global__ __launch_bounds__(256, 2) void moe_mlp(
    const ushort_t* __restrict__ xn,   // [32768][256] bf16
    const ushort_t* __restrict__ w1f,  // [8][32][16][64][8] frag-order
    const ushort_t* __restrict__ w2f,  // [8][32][16][64][8] frag-order
    const float* __restrict__ b1,      // [8][1024]
    const float* __restrict__ b2,      // [8][256]
    const int* __restrict__ cnt,       // [8]
    const int* __restrict__ lists,     // [8][65536]
    float* __restrict__ out)           // [65536][256]
{
  __shared__ __align__(16) ushort_t w1b[2][8192];     // 2 x 16KB
  __shared__ __align__(16) ushort_t w2b[2][8192];     // 2 x 16KB
  __shared__ __align__(16) ushort_t hlds[4][32][40];  // wave-private h (pad 40)
  __shared__ int prs[128];

  // locate (expert, tile) from prefix sum of per-expert tile counts
  int flat = blockIdx.x;
  int e = -1, tile = 0, accum = 0, n_e = 0;
#pragma unroll
  for (int i = 0; i < 8; ++i) {
    int c = cnt[i];
    int t = (c + 127) >> 7;
    if (e < 0 && flat < accum + t) { e = i; tile = flat - accum; n_e = c; }
    accum += t;
  }
  if (e < 0) return;
  int start = tile * 128;

  int tid = threadIdx.x;
  if (tid < 128) {
    int idx = start + tid;
    prs[tid] = (idx < n_e) ? lists[e * 65536 + idx] : lists[e * 65536];
  }

  const ushort_t* w1e = w1f + ((size_t)e << 18);
  const ushort_t* w2e = w2f + ((size_t)e << 18);
  int wave = tid >> 6, lane = tid & 63, l16 = lane & 15, quad = lane >> 4;

  // stage chunk 0 into buffer 0
  {
#pragma unroll
    for (int j = 0; j < 4; ++j) {
      int p = j * 4 + wave;
      g2l16(w1e + p * 512 + lane * 8, &w1b[0][p * 512]);
      g2l16(w2e + p * 512 + lane * 8, &w2b[0][p * 512]);
    }
  }
  __syncthreads();  // prs visible + stage(0) drained

  // A fragments: 2 m-tiles x full K=256, resident (64 VGPR)
  bf16x8 afr[2][8];
#pragma unroll
  for (int mt = 0; mt < 2; ++mt) {
    int tok = prs[wave * 32 + mt * 16 + l16] >> 1;
    const u32x4* arow = reinterpret_cast<const u32x4*>(xn + (size_t)tok * 256);
#pragma unroll
    for (int kk = 0; kk < 8; ++kk)
      afr[mt][kk] = __builtin_bit_cast(bf16x8, arow[kk * 4 + quad]);
  }

  f32x4 acc[2][16];
#pragma unroll
  for (int mt = 0; mt < 2; ++mt)
#pragma unroll
    for (int ct = 0; ct < 16; ++ct) acc[mt][ct] = (f32x4){0.f, 0.f, 0.f, 0.f};

  const float* b1e = b1 + e * 1024;

  for (int ch = 0; ch < 32; ++ch) {
    int cur = ch & 1;
    __syncthreads();  // stage(ch) complete+visible; all waves done with other buf
    if (ch + 1 < 32) {
      const ushort_t* n1 = w1e + (ch + 1) * 8192;
      const ushort_t* n2 = w2e + (ch + 1) * 8192;
#pragma unroll
      for (int j = 0; j < 4; ++j) {
        int p = j * 4 + wave;
        g2l16(n1 + p * 512 + lane * 8, &w1b[cur ^ 1][p * 512]);
        g2l16(n2 + p * 512 + lane * 8, &w2b[cur ^ 1][p * 512]);
      }
    }
    const ushort_t* l1 = w1b[cur];
    const ushort_t* l2 = w2b[cur];

    // GEMM1: h[32 rows x 32 w] over K=256
    f32x4 h1[2][2];
    h1[0][0] = (f32x4){0.f, 0.f, 0.f, 0.f};
    h1[0][1] = (f32x4){0.f, 0.f, 0.f, 0.f};
    h1[1][0] = (f32x4){0.f, 0.f, 0.f, 0.f};
    h1[1][1] = (f32x4){0.f, 0.f, 0.f, 0.f};
#pragma unroll
    for (int kk = 0; kk < 8; ++kk) {
#pragma unroll
      for (int nt = 0; nt < 2; ++nt) {
        bf16x8 b = *reinterpret_cast<const bf16x8*>(l1 + ((kk * 2 + nt) * 64 + lane) * 8);
        h1[nt][0] = __builtin_amdgcn_mfma_f32_16x16x32_bf16(afr[0][kk], b, h1[nt][0], 0, 0, 0);
        h1[nt][1] = __builtin_amdgcn_mfma_f32_16x16x32_bf16(afr[1][kk], b, h1[nt][1], 0, 0, 0);
      }
    }

    // bias + GELU(tanh approx) + relayout C->A via wave-private LDS
    int w0 = ch * 32;
#pragma unroll
    for (int nt = 0; nt < 2; ++nt) {
      float bias = b1e[w0 + nt * 16 + l16];
#pragma unroll
      for (int mt = 0; mt < 2; ++mt) {
#pragma unroll
        for (int r = 0; r < 4; ++r) {
          float v = h1[nt][mt][r] + bias;
          float u_ = v + 0.044715f * v * v * v;
          float q = __expf(1.5957691216f * u_);         // e^{2z}
          float g = v - v * __builtin_amdgcn_rcpf(1.0f + q);  // v*(1 - 1/(1+e^2z))
          hlds[wave][mt * 16 + quad * 4 + r][nt * 16 + l16] = f2bf(g);
        }
      }
    }
    bf16x8 a2_0 = *reinterpret_cast<const bf16x8*>(&hlds[wave][l16][quad * 8]);
    bf16x8 a2_1 = *reinterpret_cast<const bf16x8*>(&hlds[wave][16 + l16][quad * 8]);

    // GEMM2: y[32 rows x 256] += h[32 x 32] @ W2chunk[32 x 256]
#pragma unroll
    for (int ct = 0; ct < 16; ++ct) {
      bf16x8 b = *reinterpret_cast<const bf16x8*>(l2 + (ct * 64 + lane) * 8);
      acc[0][ct] = __builtin_amdgcn_mfma_f32_16x16x32_bf16(a2_0, b, acc[0][ct], 0, 0, 0);
      acc[1][ct] = __builtin_amdgcn_mfma_f32_16x16x32_bf16(a2_1, b, acc[1][ct], 0, 0, 0);
    }
  }

  // epilogue: +b2, masked scatter store
  const float* b2e = b2 + e * 256;
  float bl[16];
#pragma unroll
  for (int ct = 0; ct < 16; ++ct) bl[ct] = b2e[ct * 16 + l16];
#pragma unroll
  for (int mt = 0; mt < 2; ++mt) {
#pragma unroll
    for (int r = 0; r < 4; ++r) {
      int m = wave * 32 + mt * 16 + quad * 4 + r;
      if (start + m < n_e) {
        float* orow = out + (size_t)prs[m] * 256;
#pragma unroll
        for (int ct = 0; ct < 16; ++ct)
          orow[ct * 16 + l16] = acc[mt][ct][r] + bl[ct];
      }
    }
  }
}

extern "C" void kernel_launch(void* const* d_in, const int* in_sizes, int n_in,
                              void* d_out, int out_size, void* d_ws, size_t ws_size,
                              hipStream_t stream) {
  const float* x  = (const float*)d_in[0];
  const float* rw = (const float*)d_in[1];
  const float* W1 = (const float*)d_in[2];
  const float* b1 = (const float*)d_in[3];
  const float* W2 = (const float*)d_in[4];
  const float* b2 = (const float*)d_in[5];
  const int* eids = (const int*)d_in[6];
  float* out = (float*)d_out;

  char* ws = (char*)d_ws;
  ushort_t* xn  = (ushort_t*)(ws);              // 16,777,216 B
  ushort_t* w1f = (ushort_t*)(ws + 16777216);   //  4,194,304 B
  ushort_t* w2f = (ushort_t*)(ws + 20971520);   //  4,194,304 B
  int* cnt      = (int*)(ws + 25165824);        //  256 B (8 used)
  int* lists    = (int*)(ws + 25166080);        //  2,097,152 B

  hipMemsetAsync(cnt, 0, 8 * sizeof(int), stream);
  rmsnorm_cast<<<8192, 256, 0, stream>>>(x, rw, xn);
  pack_w<<<2048, 256, 0, stream>>>(W1, W2, w1f, w2f);
  route_pairs<<<256, 256, 0, stream>>>(eids, cnt, lists);
  // total tiles = sum_e ceil(n_e/128) <= 512 + 7 = 519
  moe_mlp<<<519, 256, 0, stream>>>(xn, w1f, w2f, b1, b2, cnt, lists, out);
}

// Round 3
// 253.252 us; speedup vs baseline: 3.6120x; 1.0613x over previous
//
#include <hip/hip_runtime.h>
#include <cstdint>

typedef unsigned short ushort_t;
typedef __bf16 bf16x8 __attribute__((ext_vector_type(8)));
typedef ushort_t u16x8 __attribute__((ext_vector_type(8)));
typedef float f32x4 __attribute__((ext_vector_type(4)));
typedef uint32_t u32x4 __attribute__((ext_vector_type(4)));

#define RMS_EPS 1.1920928955078125e-07f
// B=8 T=4096 C=256 Wh=1024 E=8 K=2 ; tokens NT=32768, pairs NP=65536

__device__ __forceinline__ ushort_t f2bf(float f) {
  uint32_t u = __builtin_bit_cast(uint32_t, f);
  u += 0x7fffu + ((u >> 16) & 1u);   // RNE
  return (ushort_t)(u >> 16);
}

__device__ __forceinline__ void g2l16(const ushort_t* g, ushort_t* l) {
  __builtin_amdgcn_global_load_lds(
      (const __attribute__((address_space(1))) uint32_t*)g,
      (__attribute__((address_space(3))) uint32_t*)l, 16, 0, 0);
}

// ---- RMSNorm + cast to bf16: one wave per token ----
__global__ void rmsnorm_cast(const float* __restrict__ x, const float* __restrict__ w,
                             ushort_t* __restrict__ xn) {
  int token = blockIdx.x * 4 + (threadIdx.x >> 6);
  int lane = threadIdx.x & 63;
  const float4* row = reinterpret_cast<const float4*>(x + (size_t)token * 256);
  float4 v = row[lane];
  float s = v.x * v.x + v.y * v.y + v.z * v.z + v.w * v.w;
#pragma unroll
  for (int off = 1; off < 64; off <<= 1) s += __shfl_xor(s, off);
  float inv = rsqrtf(s * (1.0f / 256.0f) + RMS_EPS);
  const float4* wr = reinterpret_cast<const float4*>(w);
  float4 wv = wr[lane];
  ushort4 o;
  o.x = f2bf(v.x * inv * wv.x);
  o.y = f2bf(v.y * inv * wv.y);
  o.z = f2bf(v.z * inv * wv.z);
  o.w = f2bf(v.w * inv * wv.w);
  *reinterpret_cast<ushort4*>(xn + (size_t)token * 256 + lane * 4) = o;
}

// ---- pack W1/W2 into MFMA B-fragment order via LDS tile (coalesced) ----
// w1f unit = e*32768 + ch*1024 + kk*128 + nt*64 + lane ; elem j = W1[e][kk*32+quad*8+j][ch*32+nt*16+l16]
// w2f unit = e*32768 + ch*1024 + ct*64 + lane          ; elem j = W2[e][ch*32+quad*8+j][ct*16+l16]
// Block: 64(k) x 128(col) tile. Blocks 0..255: W1 (kt 4 x wt 8), 256..511: W2 (kt 16 x wt 2).
__global__ __launch_bounds__(256) void pack_w(const float* __restrict__ W1,
                                              const float* __restrict__ W2,
                                              ushort_t* __restrict__ w1f,
                                              ushort_t* __restrict__ w2f) {
  __shared__ ushort_t tile[64][130];   // stride 130: 2-way-free banks on strided reads
  int b = blockIdx.x;
  int isW2 = b >= 256;
  const float* src; ushort_t* dst; int e, kt, wt, rs;
  if (!isW2) { e = b >> 5; kt = (b >> 3) & 3; wt = b & 7; src = W1; dst = w1f; rs = 1024; }
  else { b -= 256; e = b >> 5; kt = (b >> 1) & 15; wt = b & 1; src = W2; dst = w2f; rs = 256; }
  int k0 = kt * 64, c0 = wt * 128;
  const float* sb = src + ((size_t)e << 18) + (size_t)k0 * rs + c0;
  int t = threadIdx.x;
#pragma unroll
  for (int i = 0; i < 8; ++i) {
    int f = i * 1024 + t * 4;          // [0,8192)
    int r = f >> 7, c = f & 127;
    float4 v = *reinterpret_cast<const float4*>(sb + (size_t)r * rs + c);
    ushort2 lo, hi;
    lo.x = f2bf(v.x); lo.y = f2bf(v.y); hi.x = f2bf(v.z); hi.y = f2bf(v.w);
    *reinterpret_cast<ushort2*>(&tile[r][c]) = lo;
    *reinterpret_cast<ushort2*>(&tile[r][c + 2]) = hi;
  }
  __syncthreads();
  int lane = t & 63, l16 = lane & 15, quad = lane >> 4;
#pragma unroll
  for (int p = 0; p < 4; ++p) {
    int u = p * 256 + t;               // [0,1024)
    int kk2 = (u >> 9) & 1;
    int rr = kk2 * 32 + quad * 8;
    u16x8 o;
    size_t U;
    if (!isW2) {
      int nt = (u >> 6) & 1, chL = (u >> 7) & 3;
      int cc = chL * 32 + nt * 16 + l16;
#pragma unroll
      for (int j = 0; j < 8; ++j) o[j] = tile[rr + j][cc];
      U = ((size_t)e * 32768) + (size_t)(wt * 4 + chL) * 1024 + (kt * 2 + kk2) * 128 + nt * 64 + lane;
    } else {
      int ntL = (u >> 6) & 7;
      int cc = ntL * 16 + l16;
#pragma unroll
      for (int j = 0; j < 8; ++j) o[j] = tile[rr + j][cc];
      U = ((size_t)e * 32768) + (size_t)(kt * 2 + kk2) * 1024 + (wt * 8 + ntL) * 64 + lane;
    }
    *reinterpret_cast<u16x8*>(dst + U * 8) = o;
  }
}

// ---- route (t,k) pairs into per-expert lists ----
__global__ void route_pairs(const int* __restrict__ eids, int* __restrict__ cnt,
                            int* __restrict__ lists) {
  __shared__ int lcnt[8], lbase[8];
  int tid = threadIdx.x;
  if (tid < 8) lcnt[tid] = 0;
  __syncthreads();
  int p = blockIdx.x * 256 + tid;
  int e = eids[p];
  int lpos = atomicAdd(&lcnt[e], 1);
  __syncthreads();
  if (tid < 8) lbase[tid] = atomicAdd(&cnt[tid], lcnt[tid]);
  __syncthreads();
  lists[e * 65536 + lbase[e] + lpos] = p;
}

// ---- fused expert MLP ----
// 128 pairs/block, 4 waves x 32 rows. Per 32-w chunk: double-buffered LDS W1/W2
// (global_load_lds w16); GEMM1 nt-outer so GELU(nt0) overlaps GEMM1(nt1) MFMA;
// GELU sigma-form; repack via wave-private LDS; GEMM2 accumulates 32x256.
__global__ __launch_bounds__(256, 2) void moe_mlp(
    const ushort_t* __restrict__ xn,   // [32768][256] bf16
    const ushort_t* __restrict__ w1f,  // [8][32][16][64][8]
    const ushort_t* __restrict__ w2f,  // [8][32][16][64][8]
    const float* __restrict__ b1,      // [8][1024]
    const float* __restrict__ b2,      // [8][256]
    const int* __restrict__ cnt,       // [8]
    const int* __restrict__ lists,     // [8][65536]
    float* __restrict__ out)           // [65536][256]
{
  __shared__ __align__(16) ushort_t w1b[2][8192];     // 2 x 16KB
  __shared__ __align__(16) ushort_t w2b[2][8192];     // 2 x 16KB
  __shared__ __align__(16) ushort_t hlds[4][32][40];  // wave-private h
  __shared__ int prs[128];

  int flat = blockIdx.x;
  int e = -1, tile = 0, accum = 0, n_e = 0;
#pragma unroll
  for (int i = 0; i < 8; ++i) {
    int c = cnt[i];
    int t = (c + 127) >> 7;
    if (e < 0 && flat < accum + t) { e = i; tile = flat - accum; n_e = c; }
    accum += t;
  }
  if (e < 0) return;
  int start = tile * 128;

  int tid = threadIdx.x;
  if (tid < 128) {
    int idx = start + tid;
    prs[tid] = (idx < n_e) ? lists[e * 65536 + idx] : lists[e * 65536];
  }

  const ushort_t* w1e = w1f + ((size_t)e << 18);
  const ushort_t* w2e = w2f + ((size_t)e << 18);
  int wave = tid >> 6, lane = tid & 63, l16 = lane & 15, quad = lane >> 4;

  // stage chunk 0 into buffer 0
#pragma unroll
  for (int j = 0; j < 4; ++j) {
    int p = j * 4 + wave;
    g2l16(w1e + p * 512 + lane * 8, &w1b[0][p * 512]);
    g2l16(w2e + p * 512 + lane * 8, &w2b[0][p * 512]);
  }
  __syncthreads();  // prs visible + stage(0) drained

  // A fragments: 2 m-tiles x full K=256, resident (64 VGPR)
  bf16x8 afr[2][8];
#pragma unroll
  for (int mt = 0; mt < 2; ++mt) {
    int tok = prs[wave * 32 + mt * 16 + l16] >> 1;
    const u32x4* arow = reinterpret_cast<const u32x4*>(xn + (size_t)tok * 256);
#pragma unroll
    for (int kk = 0; kk < 8; ++kk)
      afr[mt][kk] = __builtin_bit_cast(bf16x8, arow[kk * 4 + quad]);
  }

  f32x4 acc[2][16];
#pragma unroll
  for (int mt = 0; mt < 2; ++mt)
#pragma unroll
    for (int ct = 0; ct < 16; ++ct) acc[mt][ct] = (f32x4){0.f, 0.f, 0.f, 0.f};

  const float* b1e = b1 + e * 1024;
  ushort_t* hl = &hlds[wave][0][0];

  for (int ch = 0; ch < 32; ++ch) {
    int cur = ch & 1;
    __syncthreads();  // stage(ch) complete+visible; all waves done with buf^1
    if (ch + 1 < 32) {
      const ushort_t* n1 = w1e + (ch + 1) * 8192;
      const ushort_t* n2 = w2e + (ch + 1) * 8192;
#pragma unroll
      for (int j = 0; j < 4; ++j) {
        int p = j * 4 + wave;
        g2l16(n1 + p * 512 + lane * 8, &w1b[cur ^ 1][p * 512]);
        g2l16(n2 + p * 512 + lane * 8, &w2b[cur ^ 1][p * 512]);
      }
    }
    const ushort_t* l1 = w1b[cur];
    const ushort_t* l2 = w2b[cur];
    int w0 = ch * 32;
    // prefetch biases early (hide L2 latency behind GEMM1)
    float bias0 = b1e[w0 + l16];
    float bias1 = b1e[w0 + 16 + l16];

    // GEMM1 nt=0: both mt chains complete first -> GELU(nt0) can overlap GEMM1(nt1)
    f32x4 h00 = (f32x4){0.f, 0.f, 0.f, 0.f};
    f32x4 h01 = (f32x4){0.f, 0.f, 0.f, 0.f};
    f32x4 h10 = (f32x4){0.f, 0.f, 0.f, 0.f};
    f32x4 h11 = (f32x4){0.f, 0.f, 0.f, 0.f};
#pragma unroll
    for (int kk = 0; kk < 8; ++kk) {
      bf16x8 bA = *reinterpret_cast<const bf16x8*>(l1 + ((kk * 2 + 0) * 64 + lane) * 8);
      h00 = __builtin_amdgcn_mfma_f32_16x16x32_bf16(afr[0][kk], bA, h00, 0, 0, 0);
      h01 = __builtin_amdgcn_mfma_f32_16x16x32_bf16(afr[1][kk], bA, h01, 0, 0, 0);
    }
#pragma unroll
    for (int kk = 0; kk < 8; ++kk) {
      bf16x8 bB = *reinterpret_cast<const bf16x8*>(l1 + ((kk * 2 + 1) * 64 + lane) * 8);
      h10 = __builtin_amdgcn_mfma_f32_16x16x32_bf16(afr[0][kk], bB, h10, 0, 0, 0);
      h11 = __builtin_amdgcn_mfma_f32_16x16x32_bf16(afr[1][kk], bB, h11, 0, 0, 0);
    }
    // GELU (v*sigmoid(2z)) + store to wave-private LDS; nt0 work is independent
    // of nt1 MFMA chains -> scheduler interleaves.
#pragma unroll
    for (int r = 0; r < 4; ++r) {
      {
        float v = h00[r] + bias0;
        float v2 = v * v;
        float u_ = (0.044715f * v2) * v + v;
        float tq = __expf(-1.5957691216057308f * u_);
        float g = v * __builtin_amdgcn_rcpf(1.0f + tq);
        hl[(quad * 4 + r) * 40 + l16] = f2bf(g);
      }
      {
        float v = h01[r] + bias0;
        float v2 = v * v;
        float u_ = (0.044715f * v2) * v + v;
        float tq = __expf(-1.5957691216057308f * u_);
        float g = v * __builtin_amdgcn_rcpf(1.0f + tq);
        hl[(16 + quad * 4 + r) * 40 + l16] = f2bf(g);
      }
      {
        float v = h10[r] + bias1;
        float v2 = v * v;
        float u_ = (0.044715f * v2) * v + v;
        float tq = __expf(-1.5957691216057308f * u_);
        float g = v * __builtin_amdgcn_rcpf(1.0f + tq);
        hl[(quad * 4 + r) * 40 + 16 + l16] = f2bf(g);
      }
      {
        float v = h11[r] + bias1;
        float v2 = v * v;
        float u_ = (0.044715f * v2) * v + v;
        float tq = __expf(-1.5957691216057308f * u_);
        float g = v * __builtin_amdgcn_rcpf(1.0f + tq);
        hl[(16 + quad * 4 + r) * 40 + 16 + l16] = f2bf(g);
      }
    }
    bf16x8 a2_0 = *reinterpret_cast<const bf16x8*>(hl + l16 * 40 + quad * 8);
    bf16x8 a2_1 = *reinterpret_cast<const bf16x8*>(hl + (16 + l16) * 40 + quad * 8);

    // GEMM2: y[32 rows x 256] += h[32 x 32] @ W2chunk[32 x 256]
#pragma unroll
    for (int ct = 0; ct < 16; ++ct) {
      bf16x8 b = *reinterpret_cast<const bf16x8*>(l2 + (ct * 64 + lane) * 8);
      acc[0][ct] = __builtin_amdgcn_mfma_f32_16x16x32_bf16(a2_0, b, acc[0][ct], 0, 0, 0);
      acc[1][ct] = __builtin_amdgcn_mfma_f32_16x16x32_bf16(a2_1, b, acc[1][ct], 0, 0, 0);
    }
  }

  // epilogue: +b2, masked scatter store
  const float* b2e = b2 + e * 256;
  float bl[16];
#pragma unroll
  for (int ct = 0; ct < 16; ++ct) bl[ct] = b2e[ct * 16 + l16];
#pragma unroll
  for (int mt = 0; mt < 2; ++mt) {
#pragma unroll
    for (int r = 0; r < 4; ++r) {
      int m = wave * 32 + mt * 16 + quad * 4 + r;
      if (start + m < n_e) {
        float* orow = out + (size_t)prs[m] * 256;
#pragma unroll
        for (int ct = 0; ct < 16; ++ct)
          orow[ct * 16 + l16] = acc[mt][ct][r] + bl[ct];
      }
    }
  }
}

extern "C" void kernel_launch(void* const* d_in, const int* in_sizes, int n_in,
                              void* d_out, int out_size, void* d_ws, size_t ws_size,
                              hipStream_t stream) {
  const float* x  = (const float*)d_in[0];
  const float* rw = (const float*)d_in[1];
  const float* W1 = (const float*)d_in[2];
  const float* b1 = (const float*)d_in[3];
  const float* W2 = (const float*)d_in[4];
  const float* b2 = (const float*)d_in[5];
  const int* eids = (const int*)d_in[6];
  float* out = (float*)d_out;

  char* ws = (char*)d_ws;
  ushort_t* xn  = (ushort_t*)(ws);              // 16,777,216 B
  ushort_t* w1f = (ushort_t*)(ws + 16777216);   //  4,194,304 B
  ushort_t* w2f = (ushort_t*)(ws + 20971520);   //  4,194,304 B
  int* cnt      = (int*)(ws + 25165824);        //  256 B (8 used)
  int* lists    = (int*)(ws + 25166080);        //  2,097,152 B

  hipMemsetAsync(cnt, 0, 8 * sizeof(int), stream);
  rmsnorm_cast<<<8192, 256, 0, stream>>>(x, rw, xn);
  pack_w<<<512, 256, 0, stream>>>(W1, W2, w1f, w2f);
  route_pairs<<<256, 256, 0, stream>>>(eids, cnt, lists);
  moe_mlp<<<519, 256, 0, stream>>>(xn, w1f, w2f, b1, b2, cnt, lists, out);
}